// Round 1
// baseline (213.022 us; speedup 1.0000x reference)
//
#include <hip/hip_runtime.h>
#include <hip/hip_bf16.h>

typedef short bf16x8 __attribute__((ext_vector_type(8)));
typedef float f32x4 __attribute__((ext_vector_type(4)));
typedef unsigned short u16;

#define MFMA16(a, b, c) __builtin_amdgcn_mfma_f32_16x16x32_bf16(a, b, c, 0, 0, 0)

__device__ inline u16 f2bf(float f) {
    unsigned u = __float_as_uint(f);
    unsigned r = (u + 0x7fffu + ((u >> 16) & 1u)) >> 16;
    return (u16)r;
}

__device__ inline void gload_lds16(const void* g, void* l) {
    __builtin_amdgcn_global_load_lds(
        (const __attribute__((address_space(1))) void*)g,
        (__attribute__((address_space(3))) void*)l, 16, 0, 0);
}

// ---------------- K0: f32 -> bf16 convert ----------------
__global__ void k_convert(const float* __restrict__ src, u16* __restrict__ dst, int n) {
    int i = (blockIdx.x * blockDim.x + threadIdx.x) * 4;
    if (i < n) {
        float4 v = *reinterpret_cast<const float4*>(src + i);
        ushort4 o;
        o.x = f2bf(v.x); o.y = f2bf(v.y); o.z = f2bf(v.z); o.w = f2bf(v.w);
        *reinterpret_cast<ushort4*>(dst + i) = o;
    }
}

// ---------------- K1: projection GEMM  Y = xb @ W^T + b ----------------
// xb [4096][1024] bf16, W [1024][1024] bf16 (row o, contiguous i)
// widx 0: Q (scaled 1/8) -> [hb][s][c];  1: K -> [hb][s][c];  2: V -> Vt [hb][c][s]
__global__ __launch_bounds__(256, 2) void k_proj(
    const u16* __restrict__ xb, const u16* __restrict__ wb,
    const float* __restrict__ bq, const float* __restrict__ bk, const float* __restrict__ bv,
    u16* __restrict__ outQ, u16* __restrict__ outK, u16* __restrict__ outVt)
{
    __shared__ __align__(16) u16 As[128 * 32];
    __shared__ __align__(16) u16 Bs[128 * 32];
    const int tid = threadIdx.x;
    const int lane = tid & 63;
    const int w = tid >> 6;
    const int widx = blockIdx.z;
    const int m0 = blockIdx.x * 128;
    const int n0 = blockIdx.y * 128;
    const u16* W = wb + widx * 1024 * 1024;
    const float* bias = (widx == 0) ? bq : ((widx == 1) ? bk : bv);

    const int wm = (w >> 1) * 64, wn = (w & 1) * 64;
    const int lm = lane & 15, lg = lane >> 4;

    f32x4 zero = {0.f, 0.f, 0.f, 0.f};
    f32x4 acc[4][4];
#pragma unroll
    for (int m = 0; m < 4; m++)
#pragma unroll
        for (int n = 0; n < 4; n++) acc[m][n] = zero;

    for (int k0 = 0; k0 < 1024; k0 += 32) {
#pragma unroll
        for (int j = 0; j < 2; j++) {
            int slot = tid + j * 256;
            int r = slot >> 2, c8 = slot & 3;
            gload_lds16(xb + (m0 + r) * 1024 + k0 + c8 * 8, As + slot * 8);
            gload_lds16(W + (n0 + r) * 1024 + k0 + c8 * 8, Bs + slot * 8);
        }
        __syncthreads();
        bf16x8 a[4], b[4];
#pragma unroll
        for (int m = 0; m < 4; m++)
            a[m] = *reinterpret_cast<const bf16x8*>(&As[(wm + m * 16 + lm) * 32 + lg * 8]);
#pragma unroll
        for (int n = 0; n < 4; n++)
            b[n] = *reinterpret_cast<const bf16x8*>(&Bs[(wn + n * 16 + lm) * 32 + lg * 8]);
#pragma unroll
        for (int m = 0; m < 4; m++)
#pragma unroll
            for (int n = 0; n < 4; n++)
                acc[m][n] = MFMA16(a[m], b[n], acc[m][n]);
        __syncthreads();
    }

#pragma unroll
    for (int n = 0; n < 4; n++) {
        int col = n0 + wn + n * 16 + lm;
        float bz = bias[col];
        int h = col >> 6, c = col & 63;
#pragma unroll
        for (int m = 0; m < 4; m++) {
#pragma unroll
            for (int r = 0; r < 4; r++) {
                int row = m0 + wm + m * 16 + lg * 4 + r;
                float v = acc[m][n][r] + bz;
                int bb = row >> 10, s = row & 1023;
                int hb = h * 4 + bb;
                if (widx == 0) {
                    outQ[(hb * 1024 + s) * 64 + c] = f2bf(v * 0.125f);
                } else if (widx == 1) {
                    outK[(hb * 1024 + s) * 64 + c] = f2bf(v);
                } else {
                    outVt[(hb * 64 + c) * 1024 + s] = f2bf(v);
                }
            }
        }
    }
}

// ---------------- K2: softmax row stats (m, 1/l) per f-row ----------------
__global__ __launch_bounds__(256, 2) void k_stats(
    const u16* __restrict__ Q, const u16* __restrict__ K,
    float* __restrict__ m_out, float* __restrict__ linv_out)
{
    const int hb = blockIdx.y;
    const int fb = blockIdx.x * 64;
    const int tid = threadIdx.x, lane = tid & 63, w = tid >> 6;
    const int lm = lane & 15, lg = lane >> 4;
    const u16* Qh = Q + hb * 1024 * 64;
    const u16* Kh = K + hb * 1024 * 64;

    const u16* qp = &Qh[(fb + w * 16 + lm) * 64 + lg * 8];
    bf16x8 a0 = *reinterpret_cast<const bf16x8*>(qp);
    bf16x8 a1 = *reinterpret_cast<const bf16x8*>(qp + 32);

    float mrun[4] = {-3e38f, -3e38f, -3e38f, -3e38f};
    float lrun[4] = {0.f, 0.f, 0.f, 0.f};

    for (int t0 = 0; t0 < 1024; t0 += 64) {
        f32x4 sacc[4];
#pragma unroll
        for (int n = 0; n < 4; n++) {
            const u16* kp = &Kh[(t0 + n * 16 + lm) * 64 + lg * 8];
            bf16x8 b0 = *reinterpret_cast<const bf16x8*>(kp);
            bf16x8 b1 = *reinterpret_cast<const bf16x8*>(kp + 32);
            f32x4 z = {0.f, 0.f, 0.f, 0.f};
            z = MFMA16(a0, b0, z);
            z = MFMA16(a1, b1, z);
            sacc[n] = z;
        }
#pragma unroll
        for (int r = 0; r < 4; r++) {
            float mx = fmaxf(fmaxf(sacc[0][r], sacc[1][r]), fmaxf(sacc[2][r], sacc[3][r]));
            mx = fmaxf(mx, __shfl_xor(mx, 1));
            mx = fmaxf(mx, __shfl_xor(mx, 2));
            mx = fmaxf(mx, __shfl_xor(mx, 4));
            mx = fmaxf(mx, __shfl_xor(mx, 8));
            float mn = fmaxf(mrun[r], mx);
            float sum = __expf(sacc[0][r] - mn) + __expf(sacc[1][r] - mn) +
                        __expf(sacc[2][r] - mn) + __expf(sacc[3][r] - mn);
            sum += __shfl_xor(sum, 1);
            sum += __shfl_xor(sum, 2);
            sum += __shfl_xor(sum, 4);
            sum += __shfl_xor(sum, 8);
            lrun[r] = lrun[r] * __expf(mrun[r] - mn) + sum;
            mrun[r] = mn;
        }
    }
    if (lm == 0) {
#pragma unroll
        for (int r = 0; r < 4; r++) {
            int f = fb + w * 16 + lg * 4 + r;
            m_out[hb * 1024 + f] = mrun[r];
            linv_out[hb * 1024 + f] = 1.0f / lrun[r];
        }
    }
}

// ---------------- K3: av[t,c] = sum_f P[f,t] * V[f,c]; interleaved store ----------------
__global__ __launch_bounds__(256, 2) void k_av(
    const u16* __restrict__ Q, const u16* __restrict__ K, const u16* __restrict__ Vt,
    const float* __restrict__ m_arr, const float* __restrict__ linv_arr,
    float* __restrict__ out)
{
    __shared__ __align__(16) u16 P_lds[64 * 72];  // [t][f], row stride 72 bf16 = 144B
    const int hb = blockIdx.y;
    const int tb = blockIdx.x * 64;
    const int tid = threadIdx.x, lane = tid & 63, w = tid >> 6;
    const int lm = lane & 15, lg = lane >> 4;
    const u16* Qh = Q + hb * 1024 * 64;
    const u16* Kh = K + hb * 1024 * 64;
    const u16* Vh = Vt + hb * 64 * 1024;
    const float* mh = m_arr + hb * 1024;
    const float* lh = linv_arr + hb * 1024;

    bf16x8 bK[4][2];
#pragma unroll
    for (int n = 0; n < 4; n++) {
        const u16* kp = &Kh[(tb + n * 16 + lm) * 64 + lg * 8];
        bK[n][0] = *reinterpret_cast<const bf16x8*>(kp);
        bK[n][1] = *reinterpret_cast<const bf16x8*>(kp + 32);
    }
    f32x4 zero = {0.f, 0.f, 0.f, 0.f};
    f32x4 accv[4];
#pragma unroll
    for (int n = 0; n < 4; n++) accv[n] = zero;

    for (int fc = 0; fc < 1024; fc += 64) {
        // S chunk: wave w computes rows f = fc + w*16 .. +16, cols = block's 64 t
        const u16* qp = &Qh[(fc + w * 16 + lm) * 64 + lg * 8];
        bf16x8 aq0 = *reinterpret_cast<const bf16x8*>(qp);
        bf16x8 aq1 = *reinterpret_cast<const bf16x8*>(qp + 32);
        f32x4 sacc[4];
#pragma unroll
        for (int n = 0; n < 4; n++) {
            f32x4 z = {0.f, 0.f, 0.f, 0.f};
            z = MFMA16(aq0, bK[n][0], z);
            z = MFMA16(aq1, bK[n][1], z);
            sacc[n] = z;
        }
        float mv[4], lv[4];
#pragma unroll
        for (int r = 0; r < 4; r++) {
            int f = fc + w * 16 + lg * 4 + r;
            mv[r] = mh[f];
            lv[r] = lh[f];
        }
#pragma unroll
        for (int n = 0; n < 4; n++) {
            ushort4 pk;
            pk.x = f2bf(__expf(sacc[n][0] - mv[0]) * lv[0]);
            pk.y = f2bf(__expf(sacc[n][1] - mv[1]) * lv[1]);
            pk.z = f2bf(__expf(sacc[n][2] - mv[2]) * lv[2]);
            pk.w = f2bf(__expf(sacc[n][3] - mv[3]) * lv[3]);
            int t_loc = n * 16 + lm;
            *reinterpret_cast<ushort4*>((char*)P_lds + t_loc * 144 + (w * 16 + lg * 4) * 2) = pk;
        }
        __syncthreads();
        // AV: A = P^T (rows t, k f), B = V (k f, cols c) from Vt [c][f]
        bf16x8 ap0 = *reinterpret_cast<const bf16x8*>((const char*)P_lds + (w * 16 + lm) * 144 + lg * 16);
        bf16x8 ap1 = *reinterpret_cast<const bf16x8*>((const char*)P_lds + (w * 16 + lm) * 144 + 64 + lg * 16);
#pragma unroll
        for (int n = 0; n < 4; n++) {
            const u16* vp = &Vh[(n * 16 + lm) * 1024 + fc + lg * 8];
            bf16x8 bv0 = *reinterpret_cast<const bf16x8*>(vp);
            bf16x8 bv1 = *reinterpret_cast<const bf16x8*>(vp + 32);
            accv[n] = MFMA16(ap0, bv0, accv[n]);
            accv[n] = MFMA16(ap1, bv1, accv[n]);
        }
        __syncthreads();
    }

    const int h = hb >> 2, bb = hb & 3;
#pragma unroll
    for (int n = 0; n < 4; n++) {
#pragma unroll
        for (int r = 0; r < 4; r++) {
            int t = tb + w * 16 + lg * 4 + r;
            int c = n * 16 + lm;
            out[(bb * 1024 + t) * 1024 + c * 16 + h] = accv[n][r];
        }
    }
}

extern "C" void kernel_launch(void* const* d_in, const int* in_sizes, int n_in,
                              void* d_out, int out_size, void* d_ws, size_t ws_size,
                              hipStream_t stream) {
    const float* x  = (const float*)d_in[0];
    const float* Wq = (const float*)d_in[1];
    const float* bq = (const float*)d_in[2];
    const float* Wk = (const float*)d_in[3];
    const float* bk = (const float*)d_in[4];
    const float* Wv = (const float*)d_in[5];
    const float* bv = (const float*)d_in[6];
    float* out = (float*)d_out;
    char* ws = (char*)d_ws;

    u16* xb = (u16*)ws;                          // 8 MB  [4096][1024]
    u16* wb = (u16*)(ws + (8u << 20));           // 6 MB  [3][1024][1024]
    u16* Qb = (u16*)(ws + (14u << 20));          // 8 MB  [64][1024][64]
    u16* Kb = (u16*)(ws + (22u << 20));          // 8 MB  [64][1024][64]
    u16* Vt = (u16*)(ws + (30u << 20));          // 8 MB  [64][64][1024]
    float* m_arr = (float*)(ws + (38u << 20));   // 256 KB
    float* linv  = (float*)(ws + (38u << 20) + (1u << 18));  // 256 KB

    k_convert<<<4096, 256, 0, stream>>>(x, xb, 4096 * 1024);
    k_convert<<<1024, 256, 0, stream>>>(Wq, wb, 1024 * 1024);
    k_convert<<<1024, 256, 0, stream>>>(Wk, wb + 1024 * 1024, 1024 * 1024);
    k_convert<<<1024, 256, 0, stream>>>(Wv, wb + 2 * 1024 * 1024, 1024 * 1024);
    k_proj<<<dim3(32, 8, 3), 256, 0, stream>>>(xb, wb, bq, bk, bv, Qb, Kb, Vt);
    k_stats<<<dim3(16, 64), 256, 0, stream>>>(Qb, Kb, m_arr, linv);
    k_av<<<dim3(16, 64), 256, 0, stream>>>(Qb, Kb, Vt, m_arr, linv, out);
}

// Round 2
// 183.470 us; speedup vs baseline: 1.1611x; 1.1611x over previous
//
#include <hip/hip_runtime.h>
#include <hip/hip_bf16.h>

typedef short bf16x8 __attribute__((ext_vector_type(8)));
typedef short bf16x4 __attribute__((ext_vector_type(4)));
typedef float f32x4 __attribute__((ext_vector_type(4)));
typedef unsigned short u16;

#define MFMA32(a, b, c) __builtin_amdgcn_mfma_f32_16x16x32_bf16(a, b, c, 0, 0, 0)

#if defined(__has_builtin)
#if __has_builtin(__builtin_amdgcn_mfma_f32_16x16x16bf16_1k)
#define HAVE_MFMA16 1
#define MFMA16(a, b, c) __builtin_amdgcn_mfma_f32_16x16x16bf16_1k(a, b, c, 0, 0, 0)
#endif
#endif
#ifndef HAVE_MFMA16
static __device__ inline f32x4 mfma16_asm(bf16x4 a, bf16x4 b, f32x4 c) {
    f32x4 d;
    asm volatile("v_mfma_f32_16x16x16_bf16 %0, %1, %2, %3\n\ts_nop 7\n\ts_nop 7"
                 : "=v"(d) : "v"(a), "v"(b), "v"(c));
    return d;
}
#define MFMA16(a, b, c) mfma16_asm(a, b, c)
#endif

__device__ inline float fexp2(float x) {
#if defined(__has_builtin) && __has_builtin(__builtin_amdgcn_exp2f)
    return __builtin_amdgcn_exp2f(x);
#else
    return exp2f(x);
#endif
}

__device__ inline u16 f2bf(float f) {
    unsigned u = __float_as_uint(f);
    unsigned r = (u + 0x7fffu + ((u >> 16) & 1u)) >> 16;
    return (u16)r;
}

__device__ inline void gload_lds16(const void* g, void* l) {
    __builtin_amdgcn_global_load_lds(
        (const __attribute__((address_space(1))) void*)g,
        (__attribute__((address_space(3))) void*)l, 16, 0, 0);
}

// ---------------- K0: f32 -> bf16 convert ----------------
__global__ void k_convert(const float* __restrict__ src, u16* __restrict__ dst, int n) {
    int i = (blockIdx.x * blockDim.x + threadIdx.x) * 4;
    if (i < n) {
        float4 v = *reinterpret_cast<const float4*>(src + i);
        ushort4 o;
        o.x = f2bf(v.x); o.y = f2bf(v.y); o.z = f2bf(v.z); o.w = f2bf(v.w);
        *reinterpret_cast<ushort4*>(dst + i) = o;
    }
}

// ---------------- K1: projection GEMM  Y = xb @ W^T + b ----------------
// widx 0: Q (scaled by 0.125*log2e) -> [hb][s][c]; 1: K -> [hb][s][c]; 2: V -> Vt [hb][c][s]
__global__ __launch_bounds__(256, 2) void k_proj(
    const u16* __restrict__ xb, const u16* __restrict__ wb,
    const float* __restrict__ bq, const float* __restrict__ bk, const float* __restrict__ bv,
    u16* __restrict__ outQ, u16* __restrict__ outK, u16* __restrict__ outVt)
{
    __shared__ __align__(16) u16 As[128 * 32];
    __shared__ __align__(16) u16 Bs[128 * 32];
    const int tid = threadIdx.x;
    const int lane = tid & 63;
    const int w = tid >> 6;
    const int widx = blockIdx.z;
    const int m0 = blockIdx.x * 128;
    const int n0 = blockIdx.y * 128;
    const u16* W = wb + widx * 1024 * 1024;
    const float* bias = (widx == 0) ? bq : ((widx == 1) ? bk : bv);

    const int wm = (w >> 1) * 64, wn = (w & 1) * 64;
    const int lm = lane & 15, lg = lane >> 4;

    f32x4 zero = {0.f, 0.f, 0.f, 0.f};
    f32x4 acc[4][4];
#pragma unroll
    for (int m = 0; m < 4; m++)
#pragma unroll
        for (int n = 0; n < 4; n++) acc[m][n] = zero;

    for (int k0 = 0; k0 < 1024; k0 += 32) {
#pragma unroll
        for (int j = 0; j < 2; j++) {
            int slot = tid + j * 256;
            int r = slot >> 2, c8 = slot & 3;
            gload_lds16(xb + (m0 + r) * 1024 + k0 + c8 * 8, As + slot * 8);
            gload_lds16(W + (n0 + r) * 1024 + k0 + c8 * 8, Bs + slot * 8);
        }
        __syncthreads();
        bf16x8 a[4], b[4];
#pragma unroll
        for (int m = 0; m < 4; m++)
            a[m] = *reinterpret_cast<const bf16x8*>(&As[(wm + m * 16 + lm) * 32 + lg * 8]);
#pragma unroll
        for (int n = 0; n < 4; n++)
            b[n] = *reinterpret_cast<const bf16x8*>(&Bs[(wn + n * 16 + lm) * 32 + lg * 8]);
#pragma unroll
        for (int m = 0; m < 4; m++)
#pragma unroll
            for (int n = 0; n < 4; n++)
                acc[m][n] = MFMA32(a[m], b[n], acc[m][n]);
        __syncthreads();
    }

#pragma unroll
    for (int n = 0; n < 4; n++) {
        int col = n0 + wn + n * 16 + lm;
        float bz = bias[col];
        int h = col >> 6, c = col & 63;
#pragma unroll
        for (int m = 0; m < 4; m++) {
#pragma unroll
            for (int r = 0; r < 4; r++) {
                int row = m0 + wm + m * 16 + lg * 4 + r;
                float v = acc[m][n][r] + bz;
                int bb = row >> 10, s = row & 1023;
                int hb = h * 4 + bb;
                if (widx == 0) {
                    // fold 1/sqrt(64) * log2(e) so softmax uses exp2 directly
                    outQ[(hb * 1024 + s) * 64 + c] = f2bf(v * 0.18033688011112042f);
                } else if (widx == 1) {
                    outK[(hb * 1024 + s) * 64 + c] = f2bf(v);
                } else {
                    outVt[(hb * 64 + c) * 1024 + s] = f2bf(v);
                }
            }
        }
    }
}

// ---------------- K2: softmax denom (1/l) per f-row, no-max variant ----------------
// l_f = sum_t 2^(S'[f,t]);  S' = (q.k/8)*log2e via Q pre-scale
__global__ __launch_bounds__(256, 2) void k_stats(
    const u16* __restrict__ Q, const u16* __restrict__ K, float* __restrict__ linv_out)
{
    const int hb = blockIdx.y;
    const int fb = blockIdx.x * 64;
    const int tid = threadIdx.x, lane = tid & 63, w = tid >> 6;
    const int lm = lane & 15, lg = lane >> 4;
    const u16* Qh = Q + hb * 65536;
    const u16* Kh = K + hb * 65536;

    const u16* qp = &Qh[(fb + w * 16 + lm) * 64 + lg * 8];
    bf16x8 a0 = *reinterpret_cast<const bf16x8*>(qp);
    bf16x8 a1 = *reinterpret_cast<const bf16x8*>(qp + 32);

    float lrun[4] = {0.f, 0.f, 0.f, 0.f};

    for (int t0 = 0; t0 < 1024; t0 += 64) {
#pragma unroll
        for (int n = 0; n < 4; n++) {
            const u16* kp = &Kh[(t0 + n * 16 + lm) * 64 + lg * 8];
            bf16x8 b0 = *reinterpret_cast<const bf16x8*>(kp);
            bf16x8 b1 = *reinterpret_cast<const bf16x8*>(kp + 32);
            f32x4 z = {0.f, 0.f, 0.f, 0.f};
            z = MFMA32(a0, b0, z);
            z = MFMA32(a1, b1, z);
            lrun[0] += fexp2(z[0]);
            lrun[1] += fexp2(z[1]);
            lrun[2] += fexp2(z[2]);
            lrun[3] += fexp2(z[3]);
        }
    }
#pragma unroll
    for (int r = 0; r < 4; r++) {
        float s = lrun[r];
        s += __shfl_xor(s, 1);
        s += __shfl_xor(s, 2);
        s += __shfl_xor(s, 4);
        s += __shfl_xor(s, 8);
        if (lm == 0)
            linv_out[hb * 1024 + fb + w * 16 + lg * 4 + r] = 1.0f / s;
    }
}

// ---------------- K3: av[t,c] = sum_f P[f,t]*V[f,c], barrier-free main loop ----------------
// S-accumulator lane layout (t=lane&15 .. via A/B roles) feeds mfma_16x16x16 A-frags directly.
__global__ __launch_bounds__(256) void k_av(
    const u16* __restrict__ Q, const u16* __restrict__ K, const u16* __restrict__ Vt,
    const float* __restrict__ linv_arr, float* __restrict__ out)
{
    __shared__ float redbuf[2][64 * 65];
    const int hb = blockIdx.y;
    const int tb = blockIdx.x * 64;
    const int tid = threadIdx.x, lane = tid & 63, w = tid >> 6;
    const int lm = lane & 15, lg = lane >> 4;
    const u16* Qh = Q + hb * 65536;
    const u16* Kh = K + hb * 65536;
    const u16* Vh = Vt + hb * 65536;
    const float* lh = linv_arr + hb * 1024;

    // K tile for this block's 64 t, kept in registers (B-operand of S-MFMA)
    bf16x8 bK[4][2];
#pragma unroll
    for (int n = 0; n < 4; n++) {
        const u16* kp = &Kh[(tb + n * 16 + lm) * 64 + lg * 8];
        bK[n][0] = *reinterpret_cast<const bf16x8*>(kp);
        bK[n][1] = *reinterpret_cast<const bf16x8*>(kp + 32);
    }

    f32x4 zero = {0.f, 0.f, 0.f, 0.f};
    f32x4 accv[4][4];  // [t-tile n][c-tile m], partial over this wave's f subset
#pragma unroll
    for (int n = 0; n < 4; n++)
#pragma unroll
        for (int m = 0; m < 4; m++) accv[n][m] = zero;

    for (int fc = 0; fc < 1024; fc += 64) {
        const int f0 = fc + w * 16;  // this wave's 16-f chunk
        const u16* qp = &Qh[(f0 + lm) * 64 + lg * 8];
        bf16x8 aq0 = *reinterpret_cast<const bf16x8*>(qp);
        bf16x8 aq1 = *reinterpret_cast<const bf16x8*>(qp + 32);
        float4 lv = *reinterpret_cast<const float4*>(&lh[f0 + lg * 4]);

        bf16x4 afrag[4];
#pragma unroll
        for (int n = 0; n < 4; n++) {
            f32x4 z = {0.f, 0.f, 0.f, 0.f};
            z = MFMA32(aq0, bK[n][0], z);
            z = MFMA32(aq1, bK[n][1], z);
            // P = 2^S' * (1/l); lane holds t = n*16+lm, f = f0+lg*4+r  == A-frag of 16x16x16
            float e0 = fexp2(z[0]) * lv.x;
            float e1 = fexp2(z[1]) * lv.y;
            float e2 = fexp2(z[2]) * lv.z;
            float e3 = fexp2(z[3]) * lv.w;
            union { __hip_bfloat162 h2[2]; bf16x4 v4; } u;
            u.h2[0] = __float22bfloat162_rn(make_float2(e0, e1));
            u.h2[1] = __float22bfloat162_rn(make_float2(e2, e3));
            afrag[n] = u.v4;
        }
#pragma unroll
        for (int m = 0; m < 4; m++) {
            bf16x4 bv = *reinterpret_cast<const bf16x4*>(&Vh[(m * 16 + lm) * 1024 + f0 + lg * 4]);
#pragma unroll
            for (int n = 0; n < 4; n++)
                accv[n][m] = MFMA16(afrag[n], bv, accv[n][m]);
        }
    }

    // cross-wave reduction: waves 2,3 seed two buffers; waves 0,1 add; then sum pair
    if (w >= 2) {
        float* B = redbuf[w - 2];
#pragma unroll
        for (int n = 0; n < 4; n++)
#pragma unroll
            for (int m = 0; m < 4; m++)
#pragma unroll
                for (int r = 0; r < 4; r++)
                    B[(n * 16 + lg * 4 + r) * 65 + m * 16 + lm] = accv[n][m][r];
    }
    __syncthreads();
    if (w < 2) {
        float* B = redbuf[w];
#pragma unroll
        for (int n = 0; n < 4; n++)
#pragma unroll
            for (int m = 0; m < 4; m++)
#pragma unroll
                for (int r = 0; r < 4; r++)
                    B[(n * 16 + lg * 4 + r) * 65 + m * 16 + lm] += accv[n][m][r];
    }
    __syncthreads();

    const int h = hb >> 2, bb = hb & 3;
#pragma unroll
    for (int j = 0; j < 16; j++) {
        int i = j * 256 + tid;
        int t_loc = i >> 6, c = i & 63;
        float v = redbuf[0][t_loc * 65 + c] + redbuf[1][t_loc * 65 + c];
        out[(bb * 1024 + tb + t_loc) * 1024 + c * 16 + h] = v;
    }
}

extern "C" void kernel_launch(void* const* d_in, const int* in_sizes, int n_in,
                              void* d_out, int out_size, void* d_ws, size_t ws_size,
                              hipStream_t stream) {
    const float* x  = (const float*)d_in[0];
    const float* Wq = (const float*)d_in[1];
    const float* bq = (const float*)d_in[2];
    const float* Wk = (const float*)d_in[3];
    const float* bk = (const float*)d_in[4];
    const float* Wv = (const float*)d_in[5];
    const float* bv = (const float*)d_in[6];
    float* out = (float*)d_out;
    char* ws = (char*)d_ws;

    u16* xb = (u16*)ws;                          // 8 MB  [4096][1024]
    u16* wb = (u16*)(ws + (8u << 20));           // 6 MB  [3][1024][1024]
    u16* Qb = (u16*)(ws + (14u << 20));          // 8 MB  [64][1024][64]
    u16* Kb = (u16*)(ws + (22u << 20));          // 8 MB  [64][1024][64]
    u16* Vt = (u16*)(ws + (30u << 20));          // 8 MB  [64][64][1024]
    float* linv  = (float*)(ws + (38u << 20));   // 256 KB

    k_convert<<<4096, 256, 0, stream>>>(x, xb, 4096 * 1024);
    k_convert<<<1024, 256, 0, stream>>>(Wq, wb, 1024 * 1024);
    k_convert<<<1024, 256, 0, stream>>>(Wk, wb + 1024 * 1024, 1024 * 1024);
    k_convert<<<1024, 256, 0, stream>>>(Wv, wb + 2 * 1024 * 1024, 1024 * 1024);
    k_proj<<<dim3(32, 8, 3), 256, 0, stream>>>(xb, wb, bq, bk, bv, Qb, Kb, Vt);
    k_stats<<<dim3(16, 64), 256, 0, stream>>>(Qb, Kb, linv);
    k_av<<<dim3(16, 64), 256, 0, stream>>>(Qb, Kb, Vt, linv, out);
}

// Round 3
// 166.795 us; speedup vs baseline: 1.2771x; 1.1000x over previous
//
#include <hip/hip_runtime.h>
#include <hip/hip_bf16.h>

typedef short bf16x8 __attribute__((ext_vector_type(8)));
typedef short bf16x4 __attribute__((ext_vector_type(4)));
typedef float f32x4 __attribute__((ext_vector_type(4)));
typedef unsigned short u16;

#define MFMA32(a, b, c) __builtin_amdgcn_mfma_f32_16x16x32_bf16(a, b, c, 0, 0, 0)

#if defined(__has_builtin)
#if __has_builtin(__builtin_amdgcn_mfma_f32_16x16x16bf16_1k)
#define HAVE_MFMA16 1
#define MFMA16(a, b, c) __builtin_amdgcn_mfma_f32_16x16x16bf16_1k(a, b, c, 0, 0, 0)
#endif
#endif
#ifndef HAVE_MFMA16
static __device__ inline f32x4 mfma16_asm(bf16x4 a, bf16x4 b, f32x4 c) {
    f32x4 d;
    asm volatile("v_mfma_f32_16x16x16_bf16 %0, %1, %2, %3\n\ts_nop 7\n\ts_nop 7"
                 : "=v"(d) : "v"(a), "v"(b), "v"(c));
    return d;
}
#define MFMA16(a, b, c) mfma16_asm(a, b, c)
#endif

__device__ inline float fexp2(float x) {
#if defined(__has_builtin) && __has_builtin(__builtin_amdgcn_exp2f)
    return __builtin_amdgcn_exp2f(x);
#else
    return exp2f(x);
#endif
}

__device__ inline u16 f2bf(float f) {
    unsigned u = __float_as_uint(f);
    unsigned r = (u + 0x7fffu + ((u >> 16) & 1u)) >> 16;
    return (u16)r;
}

__device__ inline float bf2f(u16 v) {
    return __uint_as_float(((unsigned)v) << 16);
}

__device__ inline void gload_lds16(const void* g, void* l) {
    __builtin_amdgcn_global_load_lds(
        (const __attribute__((address_space(1))) void*)g,
        (__attribute__((address_space(3))) void*)l, 16, 0, 0);
}

// stage an 8KB [64 rows][128B] tile into LDS with st-row XOR swizzle
// (source pre-swizzled; LDS dest linear per global_load_lds rules)
__device__ inline void stage8k(const u16* __restrict__ gbase, int grow_stride,
                               u16* lds, int tid) {
#pragma unroll
    for (int j = 0; j < 2; j++) {
        int o = (tid + j * 256) * 16;
        int row = o >> 7;
        int col = (o & 127) ^ ((row & 7) << 4);
        gload_lds16(gbase + row * grow_stride + (col >> 1), (u16*)((char*)lds + o));
    }
}

// swizzled byte offset inside a [64][128B] tile
__device__ inline int swz(int row, int colbyte) {
    return row * 128 + (colbyte ^ ((row & 7) << 4));
}

// ---------------- K0: f32 -> bf16 converts ----------------
__global__ void k_convert(const float* __restrict__ src, u16* __restrict__ dst, int n) {
    int i = (blockIdx.x * blockDim.x + threadIdx.x) * 4;
    if (i < n) {
        float4 v = *reinterpret_cast<const float4*>(src + i);
        ushort4 o;
        o.x = f2bf(v.x); o.y = f2bf(v.y); o.z = f2bf(v.z); o.w = f2bf(v.w);
        *reinterpret_cast<ushort4*>(dst + i) = o;
    }
}

__global__ void k_convert3(const float* __restrict__ s0, const float* __restrict__ s1,
                           const float* __restrict__ s2, u16* __restrict__ dst) {
    const float* s = (blockIdx.y == 0) ? s0 : ((blockIdx.y == 1) ? s1 : s2);
    int i = (blockIdx.x * blockDim.x + threadIdx.x) * 4;
    float4 v = *reinterpret_cast<const float4*>(s + i);
    ushort4 o;
    o.x = f2bf(v.x); o.y = f2bf(v.y); o.z = f2bf(v.z); o.w = f2bf(v.w);
    *reinterpret_cast<ushort4*>(dst + blockIdx.y * 1048576 + i) = o;
}

// ---------------- K1: projection GEMM  Y = xb @ W^T + b ----------------
// widx 0: Q (scaled by 0.125*log2e) -> [hb][s][c]; 1: K -> [hb][s][c]; 2: V -> Vt [hb][c][s]
__global__ __launch_bounds__(256, 2) void k_proj(
    const u16* __restrict__ xb, const u16* __restrict__ wb,
    const float* __restrict__ bq, const float* __restrict__ bk, const float* __restrict__ bv,
    u16* __restrict__ outQ, u16* __restrict__ outK, u16* __restrict__ outVt)
{
    __shared__ __align__(16) u16 As[128 * 32];
    __shared__ __align__(16) u16 Bs[128 * 32];
    const int tid = threadIdx.x;
    const int lane = tid & 63;
    const int w = tid >> 6;
    // bijective XCD swizzle over nwg=768 (=8*96)
    int bid = blockIdx.x + 32 * (blockIdx.y + 8 * blockIdx.z);
    int nb = (bid & 7) * 96 + (bid >> 3);
    const int m0 = (nb & 31) * 128;
    const int n0 = ((nb >> 5) & 7) * 128;
    const int widx = nb >> 8;
    const u16* W = wb + widx * 1024 * 1024;
    const float* bias = (widx == 0) ? bq : ((widx == 1) ? bk : bv);

    const int wm = (w >> 1) * 64, wn = (w & 1) * 64;
    const int lm = lane & 15, lg = lane >> 4;

    f32x4 zero = {0.f, 0.f, 0.f, 0.f};
    f32x4 acc[4][4];
#pragma unroll
    for (int m = 0; m < 4; m++)
#pragma unroll
        for (int n = 0; n < 4; n++) acc[m][n] = zero;

    for (int k0 = 0; k0 < 1024; k0 += 32) {
#pragma unroll
        for (int j = 0; j < 2; j++) {
            int slot = tid + j * 256;
            int r = slot >> 2, c8 = slot & 3;
            gload_lds16(xb + (m0 + r) * 1024 + k0 + c8 * 8, As + slot * 8);
            gload_lds16(W + (n0 + r) * 1024 + k0 + c8 * 8, Bs + slot * 8);
        }
        __syncthreads();
        bf16x8 a[4], b[4];
#pragma unroll
        for (int m = 0; m < 4; m++)
            a[m] = *reinterpret_cast<const bf16x8*>(&As[(wm + m * 16 + lm) * 32 + lg * 8]);
#pragma unroll
        for (int n = 0; n < 4; n++)
            b[n] = *reinterpret_cast<const bf16x8*>(&Bs[(wn + n * 16 + lm) * 32 + lg * 8]);
#pragma unroll
        for (int m = 0; m < 4; m++)
#pragma unroll
            for (int n = 0; n < 4; n++)
                acc[m][n] = MFMA32(a[m], b[n], acc[m][n]);
        __syncthreads();
    }

#pragma unroll
    for (int n = 0; n < 4; n++) {
        int col = n0 + wn + n * 16 + lm;
        float bz = bias[col];
        int h = col >> 6, c = col & 63;
#pragma unroll
        for (int m = 0; m < 4; m++) {
#pragma unroll
            for (int r = 0; r < 4; r++) {
                int row = m0 + wm + m * 16 + lg * 4 + r;
                float v = acc[m][n][r] + bz;
                int bb = row >> 10, s = row & 1023;
                int hb = h * 4 + bb;
                if (widx == 0) {
                    outQ[(hb * 1024 + s) * 64 + c] = f2bf(v * 0.18033688011112042f);
                } else if (widx == 1) {
                    outK[(hb * 1024 + s) * 64 + c] = f2bf(v);
                } else {
                    outVt[(hb * 64 + c) * 1024 + s] = f2bf(v);
                }
            }
        }
    }
}

// ---------------- K2: softmax denom per f-row; then scale V rows in-place ----------------
// l_f = sum_t 2^(S'[f,t]); V'[f,c] = V[f,c]/l_f  (so k_av needs no normalization)
__global__ __launch_bounds__(256, 4) void k_stats(
    const u16* __restrict__ Q, const u16* __restrict__ K, u16* __restrict__ Vt)
{
    __shared__ __align__(16) u16 sK[2][4096];
    __shared__ float linv_lds[64];
    const int hb = blockIdx.y;
    const int fb = blockIdx.x * 64;
    const int tid = threadIdx.x, lane = tid & 63, w = tid >> 6;
    const int lm = lane & 15, lg = lane >> 4;
    const u16* Qh = Q + hb * 65536;
    const u16* Kh = K + hb * 65536;
    u16* Vh = Vt + hb * 65536;

    const u16* qp = &Qh[(fb + w * 16 + lm) * 64 + lg * 8];
    bf16x8 a0 = *reinterpret_cast<const bf16x8*>(qp);
    bf16x8 a1 = *reinterpret_cast<const bf16x8*>(qp + 32);

    stage8k(Kh, 64, sK[0], tid);  // t0 = 0

    float lrun[4] = {0.f, 0.f, 0.f, 0.f};
    int cur = 0;
    for (int it = 0; it < 16; ++it) {
        if (it < 15) {
            stage8k(Kh + (it + 1) * 64 * 64, 64, sK[cur ^ 1], tid);
            asm volatile("s_waitcnt vmcnt(2)" ::: "memory");
        } else {
            asm volatile("s_waitcnt vmcnt(0)" ::: "memory");
        }
        __syncthreads();
        const char* base = (const char*)sK[cur];
#pragma unroll
        for (int n = 0; n < 4; n++) {
            int r = n * 16 + lm;
            bf16x8 b0 = *(const bf16x8*)(base + swz(r, lg * 16));
            bf16x8 b1 = *(const bf16x8*)(base + swz(r, 64 + lg * 16));
            f32x4 z = {0.f, 0.f, 0.f, 0.f};
            z = MFMA32(a0, b0, z);
            z = MFMA32(a1, b1, z);
            lrun[0] += fexp2(z[0]);
            lrun[1] += fexp2(z[1]);
            lrun[2] += fexp2(z[2]);
            lrun[3] += fexp2(z[3]);
        }
        __syncthreads();
        cur ^= 1;
    }
#pragma unroll
    for (int r = 0; r < 4; r++) {
        float s = lrun[r];
        s += __shfl_xor(s, 1);
        s += __shfl_xor(s, 2);
        s += __shfl_xor(s, 4);
        s += __shfl_xor(s, 8);
        if (lm == 0) linv_lds[w * 16 + lg * 4 + r] = 1.0f / s;
    }
    __syncthreads();
    // scale V' = V * linv over this block's 64 f columns (Vt layout [c][f])
#pragma unroll
    for (int j = 0; j < 2; j++) {
        int o = tid + j * 256;           // 0..511
        int c = o >> 3, slot = o & 7;    // 8 chunks of 8 f per c-row
        u16* vp = &Vh[c * 1024 + fb + slot * 8];
        bf16x8 v = *(const bf16x8*)vp;
        union { bf16x8 v; u16 e[8]; } uu, oo;
        uu.v = v;
#pragma unroll
        for (int i = 0; i < 8; i++)
            oo.e[i] = f2bf(bf2f(uu.e[i]) * linv_lds[slot * 8 + i]);
        *(bf16x8*)vp = oo.v;
    }
}

// ---------------- K3: av[t,c] = sum_f 2^S'[f,t] * V'[f,c] ----------------
// wave w owns t = tb + w*16 .. +16; f-loop double-buffered LDS tiles (Q,V'), swizzled.
__global__ __launch_bounds__(256, 4) void k_av(
    const u16* __restrict__ Q, const u16* __restrict__ K, const u16* __restrict__ Vt,
    float* __restrict__ out)
{
    __shared__ __align__(16) u16 sQ[2][4096];
    __shared__ __align__(16) u16 sV[2][4096];
    const int hb = blockIdx.y;
    const int tb = blockIdx.x * 64;
    const int tid = threadIdx.x, lane = tid & 63, w = tid >> 6;
    const int lm = lane & 15, lg = lane >> 4;
    const u16* Qh = Q + hb * 65536;
    const u16* Kh = K + hb * 65536;
    const u16* Vh = Vt + hb * 65536;

    // K frags for this wave's 16 t rows (B-operand of S-MFMA), one-time global load
    const u16* kp = &Kh[(tb + w * 16 + lm) * 64 + lg * 8];
    bf16x8 bK0 = *reinterpret_cast<const bf16x8*>(kp);
    bf16x8 bK1 = *reinterpret_cast<const bf16x8*>(kp + 32);

    f32x4 zero = {0.f, 0.f, 0.f, 0.f};
    f32x4 accv[4];  // 4 c-tiles x (16t x 16c), full f-sum
#pragma unroll
    for (int m = 0; m < 4; m++) accv[m] = zero;

    stage8k(Qh, 64, sQ[0], tid);      // Q rows f=0..63
    stage8k(Vh, 1024, sV[0], tid);    // V' rows c=0..63, cols f=0..63

    int cur = 0;
    for (int it = 0; it < 16; ++it) {
        if (it < 15) {
            int fn = (it + 1) * 64;
            stage8k(Qh + fn * 64, 64, sQ[cur ^ 1], tid);
            stage8k(Vh + fn, 1024, sV[cur ^ 1], tid);
            asm volatile("s_waitcnt vmcnt(4)" ::: "memory");
        } else {
            asm volatile("s_waitcnt vmcnt(0)" ::: "memory");
        }
        __syncthreads();
        const char* Qb = (const char*)sQ[cur];
        const char* Vb = (const char*)sV[cur];

        bf16x4 afrag[4];
#pragma unroll
        for (int mq = 0; mq < 4; mq++) {
            int r = mq * 16 + lm;
            bf16x8 aq0 = *(const bf16x8*)(Qb + swz(r, lg * 16));
            bf16x8 aq1 = *(const bf16x8*)(Qb + swz(r, 64 + lg * 16));
            f32x4 z = {0.f, 0.f, 0.f, 0.f};
            z = MFMA32(aq0, bK0, z);
            z = MFMA32(aq1, bK1, z);
            // lane: t = lm (wave's), f = mq*16 + lg*4 + r  == A-frag of 16x16x16
            float e0 = fexp2(z[0]);
            float e1 = fexp2(z[1]);
            float e2 = fexp2(z[2]);
            float e3 = fexp2(z[3]);
            union { __hip_bfloat162 h2[2]; bf16x4 v4; } u;
            u.h2[0] = __float22bfloat162_rn(make_float2(e0, e1));
            u.h2[1] = __float22bfloat162_rn(make_float2(e2, e3));
            afrag[mq] = u.v4;
        }
#pragma unroll
        for (int m = 0; m < 4; m++) {
            int rc = m * 16 + lm;
#pragma unroll
            for (int kc = 0; kc < 4; kc++) {
                bf16x4 bv = *(const bf16x4*)(Vb + swz(rc, kc * 32 + lg * 8));
                accv[m] = MFMA16(afrag[kc], bv, accv[m]);
            }
        }
        __syncthreads();
        cur ^= 1;
    }

    const int h = hb >> 2, bb = hb & 3;
#pragma unroll
    for (int m = 0; m < 4; m++) {
#pragma unroll
        for (int r = 0; r < 4; r++) {
            int t = tb + w * 16 + lg * 4 + r;
            int c = m * 16 + lm;
            out[(bb * 1024 + t) * 1024 + c * 16 + h] = accv[m][r];
        }
    }
}

extern "C" void kernel_launch(void* const* d_in, const int* in_sizes, int n_in,
                              void* d_out, int out_size, void* d_ws, size_t ws_size,
                              hipStream_t stream) {
    const float* x  = (const float*)d_in[0];
    const float* Wq = (const float*)d_in[1];
    const float* bq = (const float*)d_in[2];
    const float* Wk = (const float*)d_in[3];
    const float* bk = (const float*)d_in[4];
    const float* Wv = (const float*)d_in[5];
    const float* bv = (const float*)d_in[6];
    float* out = (float*)d_out;
    char* ws = (char*)d_ws;

    u16* xb = (u16*)ws;                          // 8 MB  [4096][1024]
    u16* wb = (u16*)(ws + (8u << 20));           // 6 MB  [3][1024][1024]
    u16* Qb = (u16*)(ws + (14u << 20));          // 8 MB  [64][1024][64]
    u16* Kb = (u16*)(ws + (22u << 20));          // 8 MB  [64][1024][64]
    u16* Vt = (u16*)(ws + (30u << 20));          // 8 MB  [64][64][1024]

    k_convert<<<4096, 256, 0, stream>>>(x, xb, 4096 * 1024);
    k_convert3<<<dim3(1024, 3), 256, 0, stream>>>(Wq, Wk, Wv, wb);
    k_proj<<<dim3(32, 8, 3), 256, 0, stream>>>(xb, wb, bq, bk, bv, Qb, Kb, Vt);
    k_stats<<<dim3(16, 64), 256, 0, stream>>>(Qb, Kb, Vt);
    k_av<<<dim3(16, 64), 256, 0, stream>>>(Qb, Kb, Vt, out);
}

// Round 4
// 136.606 us; speedup vs baseline: 1.5594x; 1.2210x over previous
//
#include <hip/hip_runtime.h>
#include <hip/hip_bf16.h>

typedef short bf16x8 __attribute__((ext_vector_type(8)));
typedef short bf16x4 __attribute__((ext_vector_type(4)));
typedef float f32x4 __attribute__((ext_vector_type(4)));
typedef unsigned short u16;

#define MFMA32(a, b, c) __builtin_amdgcn_mfma_f32_16x16x32_bf16(a, b, c, 0, 0, 0)

#if defined(__has_builtin)
#if __has_builtin(__builtin_amdgcn_mfma_f32_16x16x16bf16_1k)
#define HAVE_MFMA16 1
#define MFMA16(a, b, c) __builtin_amdgcn_mfma_f32_16x16x16bf16_1k(a, b, c, 0, 0, 0)
#endif
#endif
#ifndef HAVE_MFMA16
static __device__ inline f32x4 mfma16_asm(bf16x4 a, bf16x4 b, f32x4 c) {
    f32x4 d;
    asm volatile("v_mfma_f32_16x16x16_bf16 %0, %1, %2, %3\n\ts_nop 7\n\ts_nop 7"
                 : "=v"(d) : "v"(a), "v"(b), "v"(c));
    return d;
}
#define MFMA16(a, b, c) mfma16_asm(a, b, c)
#endif

__device__ inline float fexp2(float x) {
#if defined(__has_builtin) && __has_builtin(__builtin_amdgcn_exp2f)
    return __builtin_amdgcn_exp2f(x);
#else
    return exp2f(x);
#endif
}

__device__ inline u16 f2bf(float f) {
    unsigned u = __float_as_uint(f);
    unsigned r = (u + 0x7fffu + ((u >> 16) & 1u)) >> 16;
    return (u16)r;
}

__device__ inline float bf2f(u16 v) {
    return __uint_as_float(((unsigned)v) << 16);
}

__device__ inline void gload_lds16(const void* g, void* l) {
    __builtin_amdgcn_global_load_lds(
        (const __attribute__((address_space(1))) void*)g,
        (__attribute__((address_space(3))) void*)l, 16, 0, 0);
}

#define BARRIER() __builtin_amdgcn_s_barrier()

// swizzled byte offset inside a [rows][128B] tile (XOR swizzle, bank-conflict-free b128)
__device__ inline int swz(int row, int colbyte) {
    return row * 128 + (colbyte ^ ((row & 7) << 4));
}

// stage an 8KB [64 rows][128B] tile, 512 threads, 1x16B per thread (pre-swizzled source)
__device__ inline void stage8k_512(const u16* __restrict__ g, int gstride,
                                   u16* lds, int tid) {
    int o = tid * 16;
    int row = o >> 7;
    int colb = (o & 127) ^ ((row & 7) << 4);
    gload_lds16(g + row * gstride + (colb >> 1), (char*)lds + o);
}

// stage a 16KB [128 rows][128B] tile, 256 threads, 4x16B per thread
__device__ inline void stage16k_256(const u16* __restrict__ g, int gstride,
                                    u16* lds, int tid) {
#pragma unroll
    for (int j = 0; j < 4; j++) {
        int o = (tid + j * 256) * 16;
        int row = o >> 7;
        int colb = (o & 127) ^ ((row & 7) << 4);
        gload_lds16(g + row * gstride + (colb >> 1), (char*)lds + o);
    }
}

// ---------------- K0: f32 -> bf16 converts ----------------
__global__ void k_convert(const float* __restrict__ src, u16* __restrict__ dst, int n) {
    int i = (blockIdx.x * blockDim.x + threadIdx.x) * 4;
    if (i < n) {
        float4 v = *reinterpret_cast<const float4*>(src + i);
        ushort4 o;
        o.x = f2bf(v.x); o.y = f2bf(v.y); o.z = f2bf(v.z); o.w = f2bf(v.w);
        *reinterpret_cast<ushort4*>(dst + i) = o;
    }
}

__global__ void k_convert3(const float* __restrict__ s0, const float* __restrict__ s1,
                           const float* __restrict__ s2, u16* __restrict__ dst) {
    const float* s = (blockIdx.y == 0) ? s0 : ((blockIdx.y == 1) ? s1 : s2);
    int i = (blockIdx.x * blockDim.x + threadIdx.x) * 4;
    float4 v = *reinterpret_cast<const float4*>(s + i);
    ushort4 o;
    o.x = f2bf(v.x); o.y = f2bf(v.y); o.z = f2bf(v.z); o.w = f2bf(v.w);
    *reinterpret_cast<ushort4*>(dst + blockIdx.y * 1048576 + i) = o;
}

// ---------------- K1: projection GEMM  Y = xb @ W^T + b ----------------
// BK=64 swizzled tiles, double-buffered, counted vmcnt, raw barriers.
// widx 0: Q (scaled by 0.125*log2e) -> [hb][s][c]; 1: K -> [hb][s][c]; 2: V -> Vt [hb][c][s]
__global__ __launch_bounds__(256, 2) void k_proj(
    const u16* __restrict__ xb, const u16* __restrict__ wb,
    const float* __restrict__ bq, const float* __restrict__ bk, const float* __restrict__ bv,
    u16* __restrict__ outQ, u16* __restrict__ outK, u16* __restrict__ outVt)
{
    __shared__ __align__(16) u16 As[2][8192];  // [128 m][64 k] per buf
    __shared__ __align__(16) u16 Bs[2][8192];  // [128 n][64 k]
    const int tid = threadIdx.x;
    const int lane = tid & 63;
    const int w = tid >> 6;
    // bijective XCD swizzle over nwg=768 (=8*96)
    int bid = blockIdx.x + 32 * (blockIdx.y + 8 * blockIdx.z);
    int nb = (bid & 7) * 96 + (bid >> 3);
    const int m0 = (nb & 31) * 128;
    const int n0 = ((nb >> 5) & 7) * 128;
    const int widx = nb >> 8;
    const u16* W = wb + widx * 1024 * 1024;
    const float* bias = (widx == 0) ? bq : ((widx == 1) ? bk : bv);

    const int wm = (w >> 1) * 64, wn = (w & 1) * 64;
    const int lm = lane & 15, lg = lane >> 4;

    f32x4 zero = {0.f, 0.f, 0.f, 0.f};
    f32x4 acc[4][4];
#pragma unroll
    for (int m = 0; m < 4; m++)
#pragma unroll
        for (int n = 0; n < 4; n++) acc[m][n] = zero;

    stage16k_256(xb + m0 * 1024, 1024, As[0], tid);
    stage16k_256(W + n0 * 1024, 1024, Bs[0], tid);

    int cur = 0;
    for (int it = 0; it < 16; ++it) {
        if (it < 15) {
            stage16k_256(xb + m0 * 1024 + (it + 1) * 64, 1024, As[cur ^ 1], tid);
            stage16k_256(W + n0 * 1024 + (it + 1) * 64, 1024, Bs[cur ^ 1], tid);
            asm volatile("s_waitcnt vmcnt(8)" ::: "memory");
        } else {
            asm volatile("s_waitcnt vmcnt(0)" ::: "memory");
        }
        BARRIER();
        const char* Ab = (const char*)As[cur];
        const char* Bb = (const char*)Bs[cur];
#pragma unroll
        for (int kk = 0; kk < 2; kk++) {
            bf16x8 a[4], b[4];
#pragma unroll
            for (int m = 0; m < 4; m++)
                a[m] = *(const bf16x8*)(Ab + swz(wm + m * 16 + lm, kk * 64 + lg * 16));
#pragma unroll
            for (int n = 0; n < 4; n++)
                b[n] = *(const bf16x8*)(Bb + swz(wn + n * 16 + lm, kk * 64 + lg * 16));
#pragma unroll
            for (int m = 0; m < 4; m++)
#pragma unroll
                for (int n = 0; n < 4; n++)
                    acc[m][n] = MFMA32(a[m], b[n], acc[m][n]);
        }
        BARRIER();
        cur ^= 1;
    }

#pragma unroll
    for (int n = 0; n < 4; n++) {
        int col = n0 + wn + n * 16 + lm;
        float bz = bias[col];
        int h = col >> 6, c = col & 63;
#pragma unroll
        for (int m = 0; m < 4; m++) {
#pragma unroll
            for (int r = 0; r < 4; r++) {
                int row = m0 + wm + m * 16 + lg * 4 + r;
                float v = acc[m][n][r] + bz;
                int bb = row >> 10, s = row & 1023;
                int hb = h * 4 + bb;
                if (widx == 0) {
                    outQ[(hb * 1024 + s) * 64 + c] = f2bf(v * 0.18033688011112042f);
                } else if (widx == 1) {
                    outK[(hb * 1024 + s) * 64 + c] = f2bf(v);
                } else {
                    outVt[(hb * 64 + c) * 1024 + s] = f2bf(v);
                }
            }
        }
    }
}

// ---------------- K2: softmax denom per f-row; then V' = V * (1/l) in place ----------------
// 256 blocks (4 f-segs x 64 hb, XCD-grouped by hb), 512 threads; K-head streamed once/block.
__global__ __launch_bounds__(512, 2) void k_stats(
    const u16* __restrict__ Q, const u16* __restrict__ K, u16* __restrict__ Vt)
{
    __shared__ __align__(16) u16 sK[2][4096];
    __shared__ float linv_lds[256];
    const int bid = blockIdx.x;
    const int hb = (bid & 7) * 8 + ((bid >> 3) & 7);  // same-hb blocks -> same XCD
    const int fb = (bid >> 6) * 256;
    const int tid = threadIdx.x, lane = tid & 63, w = tid >> 6;
    const int lm = lane & 15, lg = lane >> 4;
    const u16* Qh = Q + hb * 65536;
    const u16* Kh = K + hb * 65536;
    u16* Vh = Vt + hb * 65536;

    // Q frags for this wave's 32 f rows (2 groups of 16)
    bf16x8 a[2][2];
#pragma unroll
    for (int fg = 0; fg < 2; fg++) {
        const u16* qp = &Qh[(fb + w * 32 + fg * 16 + lm) * 64 + lg * 8];
        a[fg][0] = *(const bf16x8*)qp;
        a[fg][1] = *(const bf16x8*)(qp + 32);
    }

    float lrun[2][4] = {{0.f, 0.f, 0.f, 0.f}, {0.f, 0.f, 0.f, 0.f}};

    stage8k_512(Kh, 64, sK[0], tid);
    int cur = 0;
    for (int it = 0; it < 16; ++it) {
        if (it < 15) {
            stage8k_512(Kh + (it + 1) * 64 * 64, 64, sK[cur ^ 1], tid);
            asm volatile("s_waitcnt vmcnt(1)" ::: "memory");
        } else {
            asm volatile("s_waitcnt vmcnt(0)" ::: "memory");
        }
        BARRIER();
        const char* base = (const char*)sK[cur];
#pragma unroll
        for (int n = 0; n < 4; n++) {
            int r = n * 16 + lm;
            bf16x8 b0 = *(const bf16x8*)(base + swz(r, lg * 16));
            bf16x8 b1 = *(const bf16x8*)(base + swz(r, 64 + lg * 16));
#pragma unroll
            for (int fg = 0; fg < 2; fg++) {
                f32x4 z = {0.f, 0.f, 0.f, 0.f};
                z = MFMA32(a[fg][0], b0, z);
                z = MFMA32(a[fg][1], b1, z);
                lrun[fg][0] += fexp2(z[0]);
                lrun[fg][1] += fexp2(z[1]);
                lrun[fg][2] += fexp2(z[2]);
                lrun[fg][3] += fexp2(z[3]);
            }
        }
        BARRIER();
        cur ^= 1;
    }
#pragma unroll
    for (int fg = 0; fg < 2; fg++) {
#pragma unroll
        for (int r = 0; r < 4; r++) {
            float s = lrun[fg][r];
            s += __shfl_xor(s, 1);
            s += __shfl_xor(s, 2);
            s += __shfl_xor(s, 4);
            s += __shfl_xor(s, 8);
            if (lm == 0) linv_lds[w * 32 + fg * 16 + lg * 4 + r] = 1.0f / s;
        }
    }
    __syncthreads();
    // V' = V * linv over this block's 256-f slice (Vt layout [c][f])
    {
        int c = tid >> 3, f8 = tid & 7;
#pragma unroll
        for (int j = 0; j < 4; j++) {
            int fl = f8 * 8 + j * 64;
            u16* vp = &Vh[c * 1024 + fb + fl];
            union { bf16x8 v; u16 e[8]; } uu, oo;
            uu.v = *(const bf16x8*)vp;
#pragma unroll
            for (int i = 0; i < 8; i++)
                oo.e[i] = f2bf(bf2f(uu.e[i]) * linv_lds[fl + i]);
            *(bf16x8*)vp = oo.v;
        }
    }
}

// ---------------- K3: av[t,c] = sum_f 2^S'[f,t] * V'[f,c] ----------------
// 256 blocks (4 t-segs x 64 hb, XCD-grouped), 512 threads; Q/V heads streamed once/block.
__global__ __launch_bounds__(512, 2) void k_av(
    const u16* __restrict__ Q, const u16* __restrict__ K, const u16* __restrict__ Vt,
    float* __restrict__ out)
{
    __shared__ __align__(16) u16 sQ[2][4096];
    __shared__ __align__(16) u16 sV[2][4096];
    const int bid = blockIdx.x;
    const int hb = (bid & 7) * 8 + ((bid >> 3) & 7);
    const int tb = (bid >> 6) * 256;
    const int tid = threadIdx.x, lane = tid & 63, w = tid >> 6;
    const int lm = lane & 15, lg = lane >> 4;
    const u16* Qh = Q + hb * 65536;
    const u16* Kh = K + hb * 65536;
    const u16* Vh = Vt + hb * 65536;

    // K frags for this wave's 32 t rows (2 groups of 16)
    bf16x8 bK[2][2];
#pragma unroll
    for (int tg = 0; tg < 2; tg++) {
        const u16* kp = &Kh[(tb + w * 32 + tg * 16 + lm) * 64 + lg * 8];
        bK[tg][0] = *(const bf16x8*)kp;
        bK[tg][1] = *(const bf16x8*)(kp + 32);
    }

    f32x4 zero = {0.f, 0.f, 0.f, 0.f};
    f32x4 accv[2][4];  // [tg][c-tile m]
#pragma unroll
    for (int tg = 0; tg < 2; tg++)
#pragma unroll
        for (int m = 0; m < 4; m++) accv[tg][m] = zero;

    stage8k_512(Qh, 64, sQ[0], tid);
    stage8k_512(Vh, 1024, sV[0], tid);

    int cur = 0;
    for (int it = 0; it < 16; ++it) {
        if (it < 15) {
            int fn = (it + 1) * 64;
            stage8k_512(Qh + fn * 64, 64, sQ[cur ^ 1], tid);
            stage8k_512(Vh + fn, 1024, sV[cur ^ 1], tid);
            asm volatile("s_waitcnt vmcnt(2)" ::: "memory");
        } else {
            asm volatile("s_waitcnt vmcnt(0)" ::: "memory");
        }
        BARRIER();
        const char* Qb = (const char*)sQ[cur];
        const char* Vb = (const char*)sV[cur];

        // V' B-frags for MFMA16: [m: c-tile][kc: f-chunk]
        bf16x4 bv[4][4];
#pragma unroll
        for (int m = 0; m < 4; m++)
#pragma unroll
            for (int kc = 0; kc < 4; kc++)
                bv[m][kc] = *(const bf16x4*)(Vb + swz(m * 16 + lm, kc * 32 + lg * 8));

        // P fragments: S via MFMA32 (lane: t=lm, f=lg*4+r) == A-frag of 16x16x16
        bf16x4 afrag[2][4];
#pragma unroll
        for (int mq = 0; mq < 4; mq++) {
            bf16x8 aq0 = *(const bf16x8*)(Qb + swz(mq * 16 + lm, lg * 16));
            bf16x8 aq1 = *(const bf16x8*)(Qb + swz(mq * 16 + lm, 64 + lg * 16));
#pragma unroll
            for (int tg = 0; tg < 2; tg++) {
                f32x4 z = {0.f, 0.f, 0.f, 0.f};
                z = MFMA32(aq0, bK[tg][0], z);
                z = MFMA32(aq1, bK[tg][1], z);
                union { __hip_bfloat162 h2[2]; bf16x4 v4; } u;
                u.h2[0] = __float22bfloat162_rn(make_float2(fexp2(z[0]), fexp2(z[1])));
                u.h2[1] = __float22bfloat162_rn(make_float2(fexp2(z[2]), fexp2(z[3])));
                afrag[tg][mq] = u.v4;
            }
        }
#pragma unroll
        for (int tg = 0; tg < 2; tg++)
#pragma unroll
            for (int m = 0; m < 4; m++)
#pragma unroll
                for (int kc = 0; kc < 4; kc++)
                    accv[tg][m] = MFMA16(afrag[tg][kc], bv[m][kc], accv[tg][m]);
        BARRIER();
        cur ^= 1;
    }

    const int h = hb >> 2, bb = hb & 3;
#pragma unroll
    for (int tg = 0; tg < 2; tg++) {
#pragma unroll
        for (int m = 0; m < 4; m++) {
#pragma unroll
            for (int r = 0; r < 4; r++) {
                int t = tb + w * 32 + tg * 16 + lg * 4 + r;
                int c = m * 16 + lm;
                out[(bb * 1024 + t) * 1024 + c * 16 + h] = accv[tg][m][r];
            }
        }
    }
}

extern "C" void kernel_launch(void* const* d_in, const int* in_sizes, int n_in,
                              void* d_out, int out_size, void* d_ws, size_t ws_size,
                              hipStream_t stream) {
    const float* x  = (const float*)d_in[0];
    const float* Wq = (const float*)d_in[1];
    const float* bq = (const float*)d_in[2];
    const float* Wk = (const float*)d_in[3];
    const float* bk = (const float*)d_in[4];
    const float* Wv = (const float*)d_in[5];
    const float* bv = (const float*)d_in[6];
    float* out = (float*)d_out;
    char* ws = (char*)d_ws;

    u16* xb = (u16*)ws;                          // 8 MB  [4096][1024]
    u16* wb = (u16*)(ws + (8u << 20));           // 6 MB  [3][1024][1024]
    u16* Qb = (u16*)(ws + (14u << 20));          // 8 MB  [64][1024][64]
    u16* Kb = (u16*)(ws + (22u << 20));          // 8 MB  [64][1024][64]
    u16* Vt = (u16*)(ws + (30u << 20));          // 8 MB  [64][64][1024]

    k_convert<<<4096, 256, 0, stream>>>(x, xb, 4096 * 1024);
    k_convert3<<<dim3(1024, 3), 256, 0, stream>>>(Wq, Wk, Wv, wb);
    k_proj<<<dim3(32, 8, 3), 256, 0, stream>>>(xb, wb, bq, bk, bv, Qb, Kb, Vt);
    k_stats<<<256, 512, 0, stream>>>(Qb, Kb, Vt);
    k_av<<<256, 512, 0, stream>>>(Qb, Kb, Vt, out);
}

// Round 5
// 117.798 us; speedup vs baseline: 1.8084x; 1.1597x over previous
//
#include <hip/hip_runtime.h>
#include <hip/hip_bf16.h>

typedef short bf16x8 __attribute__((ext_vector_type(8)));
typedef short bf16x4 __attribute__((ext_vector_type(4)));
typedef float f32x4 __attribute__((ext_vector_type(4)));
typedef unsigned short u16;

#define MFMA32(a, b, c) __builtin_amdgcn_mfma_f32_16x16x32_bf16(a, b, c, 0, 0, 0)

#if defined(__has_builtin)
#if __has_builtin(__builtin_amdgcn_mfma_f32_16x16x16bf16_1k)
#define HAVE_MFMA16 1
#define MFMA16(a, b, c) __builtin_amdgcn_mfma_f32_16x16x16bf16_1k(a, b, c, 0, 0, 0)
#endif
#endif
#ifndef HAVE_MFMA16
static __device__ inline f32x4 mfma16_asm(bf16x4 a, bf16x4 b, f32x4 c) {
    f32x4 d;
    asm volatile("v_mfma_f32_16x16x16_bf16 %0, %1, %2, %3\n\ts_nop 7\n\ts_nop 7"
                 : "=v"(d) : "v"(a), "v"(b), "v"(c));
    return d;
}
#define MFMA16(a, b, c) mfma16_asm(a, b, c)
#endif

__device__ inline float fexp2(float x) {
#if defined(__has_builtin) && __has_builtin(__builtin_amdgcn_exp2f)
    return __builtin_amdgcn_exp2f(x);
#else
    return exp2f(x);
#endif
}

__device__ inline u16 f2bf(float f) {
    unsigned u = __float_as_uint(f);
    unsigned r = (u + 0x7fffu + ((u >> 16) & 1u)) >> 16;
    return (u16)r;
}

__device__ inline float bf2f(u16 v) {
    return __uint_as_float(((unsigned)v) << 16);
}

__device__ inline void gload_lds16(const void* g, void* l) {
    __builtin_amdgcn_global_load_lds(
        (const __attribute__((address_space(1))) void*)g,
        (__attribute__((address_space(3))) void*)l, 16, 0, 0);
}

#define BARRIER() __builtin_amdgcn_s_barrier()

// swizzled byte offset inside a [rows][128B] tile (XOR swizzle, bank-conflict-free b128)
__device__ inline int swz(int row, int colbyte) {
    return row * 128 + (colbyte ^ ((row & 7) << 4));
}

// stage an 8KB [64 rows][128B] tile, 512 threads, 1x16B per thread (pre-swizzled source)
__device__ inline void stage8k_512(const u16* __restrict__ g, int gstride,
                                   u16* lds, int tid) {
    int o = tid * 16;
    int row = o >> 7;
    int colb = (o & 127) ^ ((row & 7) << 4);
    gload_lds16(g + row * gstride + (colb >> 1), (char*)lds + o);
}

// stage a 16KB [128 rows][128B] tile, 256 threads, 4x16B per thread
__device__ inline void stage16k_256(const u16* __restrict__ g, int gstride,
                                    u16* lds, int tid) {
#pragma unroll
    for (int j = 0; j < 4; j++) {
        int o = (tid + j * 256) * 16;
        int row = o >> 7;
        int colb = (o & 127) ^ ((row & 7) << 4);
        gload_lds16(g + row * gstride + (colb >> 1), (char*)lds + o);
    }
}

// ---------------- K0: f32 -> bf16 converts ----------------
__global__ void k_convert(const float* __restrict__ src, u16* __restrict__ dst, int n) {
    int i = (blockIdx.x * blockDim.x + threadIdx.x) * 4;
    if (i < n) {
        float4 v = *reinterpret_cast<const float4*>(src + i);
        ushort4 o;
        o.x = f2bf(v.x); o.y = f2bf(v.y); o.z = f2bf(v.z); o.w = f2bf(v.w);
        *reinterpret_cast<ushort4*>(dst + i) = o;
    }
}

__global__ void k_convert3(const float* __restrict__ s0, const float* __restrict__ s1,
                           const float* __restrict__ s2, u16* __restrict__ dst) {
    const float* s = (blockIdx.y == 0) ? s0 : ((blockIdx.y == 1) ? s1 : s2);
    int i = (blockIdx.x * blockDim.x + threadIdx.x) * 4;
    float4 v = *reinterpret_cast<const float4*>(s + i);
    ushort4 o;
    o.x = f2bf(v.x); o.y = f2bf(v.y); o.z = f2bf(v.z); o.w = f2bf(v.w);
    *reinterpret_cast<ushort4*>(dst + blockIdx.y * 1048576 + i) = o;
}

// ---------------- K1: projection GEMM  Y = xb @ W^T + b ----------------
// m97 structure: BK=64, SINGLE-buffered 32KB LDS (4-5 blocks/CU), conflict-free
// XOR-swizzled tiles, 2 barriers/K-step. XCD-2D panel partition: XCD x owns
// an 8m x 12n sub-grid so its L2 holds 2MB xb panels + 3MB W panels.
// widx 0: Q (scaled by 0.125*log2e) -> [hb][s][c]; 1: K -> [hb][s][c]; 2: V -> Vt [hb][c][s]
__global__ __launch_bounds__(256, 3) void k_proj(
    const u16* __restrict__ xb, const u16* __restrict__ wb,
    const float* __restrict__ bq, const float* __restrict__ bk, const float* __restrict__ bv,
    u16* __restrict__ outQ, u16* __restrict__ outK, u16* __restrict__ outVt)
{
    __shared__ __align__(16) u16 As[8192];  // [128 m][64 k] swizzled
    __shared__ __align__(16) u16 Bs[8192];  // [128 n][64 k] swizzled
    const int tid = threadIdx.x;
    const int lane = tid & 63;
    const int w = tid >> 6;
    // XCD-aware 2-D partition over the 32m x 24n panel grid (768 blocks):
    // xcd = bid%8 (HW round-robin); xcd owns tile (mg=xcd&3, ng=xcd>>2) of 8m x 12n.
    const int bid = blockIdx.x;
    const int xcd = bid & 7, idx = bid >> 3;           // idx 0..95
    const int mg = xcd & 3, ng = xcd >> 2;
    const int m0 = (mg * 8 + (idx & 7)) * 128;
    const int nfull = ng * 12 + (idx >> 3);            // 0..23
    const int widx = nfull >> 3;
    const int n0 = (nfull & 7) * 128;
    const u16* W = wb + widx * 1024 * 1024;
    const float* bias = (widx == 0) ? bq : ((widx == 1) ? bk : bv);

    const int wm = (w >> 1) * 64, wn = (w & 1) * 64;
    const int lm = lane & 15, lg = lane >> 4;

    f32x4 zero = {0.f, 0.f, 0.f, 0.f};
    f32x4 acc[4][4];
#pragma unroll
    for (int m = 0; m < 4; m++)
#pragma unroll
        for (int n = 0; n < 4; n++) acc[m][n] = zero;

    for (int it = 0; it < 16; ++it) {
        stage16k_256(xb + m0 * 1024 + it * 64, 1024, As, tid);
        stage16k_256(W + n0 * 1024 + it * 64, 1024, Bs, tid);
        __syncthreads();   // drains vmcnt(0): staging complete
        const char* Ab = (const char*)As;
        const char* Bb = (const char*)Bs;
#pragma unroll
        for (int kk = 0; kk < 2; kk++) {
            bf16x8 a[4], b[4];
#pragma unroll
            for (int m = 0; m < 4; m++)
                a[m] = *(const bf16x8*)(Ab + swz(wm + m * 16 + lm, kk * 64 + lg * 16));
#pragma unroll
            for (int n = 0; n < 4; n++)
                b[n] = *(const bf16x8*)(Bb + swz(wn + n * 16 + lm, kk * 64 + lg * 16));
#pragma unroll
            for (int m = 0; m < 4; m++)
#pragma unroll
                for (int n = 0; n < 4; n++)
                    acc[m][n] = MFMA32(a[m], b[n], acc[m][n]);
        }
        __syncthreads();   // reads done before next stage overwrites
    }

#pragma unroll
    for (int n = 0; n < 4; n++) {
        int col = n0 + wn + n * 16 + lm;
        float bz = bias[col];
        int h = col >> 6, c = col & 63;
#pragma unroll
        for (int m = 0; m < 4; m++) {
#pragma unroll
            for (int r = 0; r < 4; r++) {
                int row = m0 + wm + m * 16 + lg * 4 + r;
                float v = acc[m][n][r] + bz;
                int bb = row >> 10, s = row & 1023;
                int hb = h * 4 + bb;
                if (widx == 0) {
                    outQ[(hb * 1024 + s) * 64 + c] = f2bf(v * 0.18033688011112042f);
                } else if (widx == 1) {
                    outK[(hb * 1024 + s) * 64 + c] = f2bf(v);
                } else {
                    outVt[(hb * 64 + c) * 1024 + s] = f2bf(v);
                }
            }
        }
    }
}

// ---------------- K2: softmax denom per f-row; then V' = V * (1/l) in place ----------------
// 256 blocks (4 f-segs x 64 hb, XCD-grouped by hb), 512 threads; K-head streamed once/block.
__global__ __launch_bounds__(512, 2) void k_stats(
    const u16* __restrict__ Q, const u16* __restrict__ K, u16* __restrict__ Vt)
{
    __shared__ __align__(16) u16 sK[2][4096];
    __shared__ float linv_lds[256];
    const int bid = blockIdx.x;
    const int hb = (bid & 7) * 8 + ((bid >> 3) & 7);  // same-hb blocks -> same XCD
    const int fb = (bid >> 6) * 256;
    const int tid = threadIdx.x, lane = tid & 63, w = tid >> 6;
    const int lm = lane & 15, lg = lane >> 4;
    const u16* Qh = Q + hb * 65536;
    const u16* Kh = K + hb * 65536;
    u16* Vh = Vt + hb * 65536;

    // Q frags for this wave's 32 f rows (2 groups of 16)
    bf16x8 a[2][2];
#pragma unroll
    for (int fg = 0; fg < 2; fg++) {
        const u16* qp = &Qh[(fb + w * 32 + fg * 16 + lm) * 64 + lg * 8];
        a[fg][0] = *(const bf16x8*)qp;
        a[fg][1] = *(const bf16x8*)(qp + 32);
    }

    float lrun[2][4] = {{0.f, 0.f, 0.f, 0.f}, {0.f, 0.f, 0.f, 0.f}};

    stage8k_512(Kh, 64, sK[0], tid);
    int cur = 0;
    for (int it = 0; it < 16; ++it) {
        if (it < 15) {
            stage8k_512(Kh + (it + 1) * 64 * 64, 64, sK[cur ^ 1], tid);
            asm volatile("s_waitcnt vmcnt(1)" ::: "memory");
        } else {
            asm volatile("s_waitcnt vmcnt(0)" ::: "memory");
        }
        BARRIER();
        const char* base = (const char*)sK[cur];
#pragma unroll
        for (int n = 0; n < 4; n++) {
            int r = n * 16 + lm;
            bf16x8 b0 = *(const bf16x8*)(base + swz(r, lg * 16));
            bf16x8 b1 = *(const bf16x8*)(base + swz(r, 64 + lg * 16));
#pragma unroll
            for (int fg = 0; fg < 2; fg++) {
                f32x4 z = {0.f, 0.f, 0.f, 0.f};
                z = MFMA32(a[fg][0], b0, z);
                z = MFMA32(a[fg][1], b1, z);
                lrun[fg][0] += fexp2(z[0]);
                lrun[fg][1] += fexp2(z[1]);
                lrun[fg][2] += fexp2(z[2]);
                lrun[fg][3] += fexp2(z[3]);
            }
        }
        BARRIER();
        cur ^= 1;
    }
#pragma unroll
    for (int fg = 0; fg < 2; fg++) {
#pragma unroll
        for (int r = 0; r < 4; r++) {
            float s = lrun[fg][r];
            s += __shfl_xor(s, 1);
            s += __shfl_xor(s, 2);
            s += __shfl_xor(s, 4);
            s += __shfl_xor(s, 8);
            if (lm == 0) linv_lds[w * 32 + fg * 16 + lg * 4 + r] = 1.0f / s;
        }
    }
    __syncthreads();
    // V' = V * linv over this block's 256-f slice (Vt layout [c][f])
    {
        int c = tid >> 3, f8 = tid & 7;
#pragma unroll
        for (int j = 0; j < 4; j++) {
            int fl = f8 * 8 + j * 64;
            u16* vp = &Vh[c * 1024 + fb + fl];
            union { bf16x8 v; u16 e[8]; } uu, oo;
            uu.v = *(const bf16x8*)vp;
#pragma unroll
            for (int i = 0; i < 8; i++)
                oo.e[i] = f2bf(bf2f(uu.e[i]) * linv_lds[fl + i]);
            *(bf16x8*)vp = oo.v;
        }
    }
}

// ---------------- K3: av[t,c] = sum_f 2^S'[f,t] * V'[f,c] ----------------
// 256 blocks (4 t-segs x 64 hb, XCD-grouped), 512 threads; Q/V heads streamed once/block.
__global__ __launch_bounds__(512, 2) void k_av(
    const u16* __restrict__ Q, const u16* __restrict__ K, const u16* __restrict__ Vt,
    float* __restrict__ out)
{
    __shared__ __align__(16) u16 sQ[2][4096];
    __shared__ __align__(16) u16 sV[2][4096];
    const int bid = blockIdx.x;
    const int hb = (bid & 7) * 8 + ((bid >> 3) & 7);
    const int tb = (bid >> 6) * 256;
    const int tid = threadIdx.x, lane = tid & 63, w = tid >> 6;
    const int lm = lane & 15, lg = lane >> 4;
    const u16* Qh = Q + hb * 65536;
    const u16* Kh = K + hb * 65536;
    const u16* Vh = Vt + hb * 65536;

    // K frags for this wave's 32 t rows (2 groups of 16)
    bf16x8 bK[2][2];
#pragma unroll
    for (int tg = 0; tg < 2; tg++) {
        const u16* kp = &Kh[(tb + w * 32 + tg * 16 + lm) * 64 + lg * 8];
        bK[tg][0] = *(const bf16x8*)kp;
        bK[tg][1] = *(const bf16x8*)(kp + 32);
    }

    f32x4 zero = {0.f, 0.f, 0.f, 0.f};
    f32x4 accv[2][4];  // [tg][c-tile m]
#pragma unroll
    for (int tg = 0; tg < 2; tg++)
#pragma unroll
        for (int m = 0; m < 4; m++) accv[tg][m] = zero;

    stage8k_512(Qh, 64, sQ[0], tid);
    stage8k_512(Vh, 1024, sV[0], tid);

    int cur = 0;
    for (int it = 0; it < 16; ++it) {
        if (it < 15) {
            int fn = (it + 1) * 64;
            stage8k_512(Qh + fn * 64, 64, sQ[cur ^ 1], tid);
            stage8k_512(Vh + fn, 1024, sV[cur ^ 1], tid);
            asm volatile("s_waitcnt vmcnt(2)" ::: "memory");
        } else {
            asm volatile("s_waitcnt vmcnt(0)" ::: "memory");
        }
        BARRIER();
        const char* Qb = (const char*)sQ[cur];
        const char* Vb = (const char*)sV[cur];

        // V' B-frags for MFMA16: [m: c-tile][kc: f-chunk]
        bf16x4 bv[4][4];
#pragma unroll
        for (int m = 0; m < 4; m++)
#pragma unroll
            for (int kc = 0; kc < 4; kc++)
                bv[m][kc] = *(const bf16x4*)(Vb + swz(m * 16 + lm, kc * 32 + lg * 8));

        // P fragments: S via MFMA32 (lane: t=lm, f=lg*4+r) == A-frag of 16x16x16
        bf16x4 afrag[2][4];
#pragma unroll
        for (int mq = 0; mq < 4; mq++) {
            bf16x8 aq0 = *(const bf16x8*)(Qb + swz(mq * 16 + lm, lg * 16));
            bf16x8 aq1 = *(const bf16x8*)(Qb + swz(mq * 16 + lm, 64 + lg * 16));
#pragma unroll
            for (int tg = 0; tg < 2; tg++) {
                f32x4 z = {0.f, 0.f, 0.f, 0.f};
                z = MFMA32(aq0, bK[tg][0], z);
                z = MFMA32(aq1, bK[tg][1], z);
                union { __hip_bfloat162 h2[2]; bf16x4 v4; } u;
                u.h2[0] = __float22bfloat162_rn(make_float2(fexp2(z[0]), fexp2(z[1])));
                u.h2[1] = __float22bfloat162_rn(make_float2(fexp2(z[2]), fexp2(z[3])));
                afrag[tg][mq] = u.v4;
            }
        }
#pragma unroll
        for (int tg = 0; tg < 2; tg++)
#pragma unroll
            for (int m = 0; m < 4; m++)
#pragma unroll
                for (int kc = 0; kc < 4; kc++)
                    accv[tg][m] = MFMA16(afrag[tg][kc], bv[m][kc], accv[tg][m]);
        BARRIER();
        cur ^= 1;
    }

    const int h = hb >> 2, bb = hb & 3;
#pragma unroll
    for (int tg = 0; tg < 2; tg++) {
#pragma unroll
        for (int m = 0; m < 4; m++) {
#pragma unroll
            for (int r = 0; r < 4; r++) {
                int t = tb + w * 32 + tg * 16 + lg * 4 + r;
                int c = m * 16 + lm;
                out[(bb * 1024 + t) * 1024 + c * 16 + h] = accv[tg][m][r];
            }
        }
    }
}

extern "C" void kernel_launch(void* const* d_in, const int* in_sizes, int n_in,
                              void* d_out, int out_size, void* d_ws, size_t ws_size,
                              hipStream_t stream) {
    const float* x  = (const float*)d_in[0];
    const float* Wq = (const float*)d_in[1];
    const float* bq = (const float*)d_in[2];
    const float* Wk = (const float*)d_in[3];
    const float* bk = (const float*)d_in[4];
    const float* Wv = (const float*)d_in[5];
    const float* bv = (const float*)d_in[6];
    float* out = (float*)d_out;
    char* ws = (char*)d_ws;

    u16* xb = (u16*)ws;                          // 8 MB  [4096][1024]
    u16* wb = (u16*)(ws + (8u << 20));           // 6 MB  [3][1024][1024]
    u16* Qb = (u16*)(ws + (14u << 20));          // 8 MB  [64][1024][64]
    u16* Kb = (u16*)(ws + (22u << 20));          // 8 MB  [64][1024][64]
    u16* Vt = (u16*)(ws + (30u << 20));          // 8 MB  [64][64][1024]

    k_convert<<<4096, 256, 0, stream>>>(x, xb, 4096 * 1024);
    k_convert3<<<dim3(1024, 3), 256, 0, stream>>>(Wq, Wk, Wv, wb);
    k_proj<<<768, 256, 0, stream>>>(xb, wb, bq, bk, bv, Qb, Kb, Vt);
    k_stats<<<256, 512, 0, stream>>>(Qb, Kb, Vt);
    k_av<<<256, 512, 0, stream>>>(Qb, Kb, Vt, out);
}